// Round 3
// baseline (10887.951 us; speedup 1.0000x reference)
//
#include <hip/hip_runtime.h>
#include <hip/hip_fp16.h>
#include <math.h>
#include <stdint.h>

// MobiusGRU T=256 B=64 D=H=512, 2 layers.
// R10 = R7's column-split dot layout + R8's compute-everything-locally math.
// Per step only TWO cross-WG exchange rounds:
//   round 1: a_z, a_r dot vectors (each WG posts own 128 cols, polls rest)
//   round 2: cel candidate dot vector (same pattern)
// All norms/stats, both gates, wv, the Mobius tail and h_new are computed
// redundantly by every WG (bitwise-identical: same posted values summed in
// the same fixed order). No h broadcast, no wv broadcast, no scalar rounds.
// 7 barriers/step (was 10), 2 remote rounds (was 5). Own-column values are
// read from LDS instead of polled (skips self fabric round trip).
// Fence-free tagged {tag,value} u64 relaxed agent atomics, interlocked so a
// slot is only reposted after all its readers finished the previous step.

#define T_  256
#define B_  64
#define H_  512
#define G3_ 1536
#define EPSF 1e-15f
#define CLIPF (1.0f - 1e-5f)
#define SCOPE_AGENT __HIP_MEMORY_SCOPE_AGENT

typedef _Float16 v2h __attribute__((ext_vector_type(2)));

__device__ __forceinline__ float fdot2_(unsigned int w, unsigned int h, float c){
#if __has_builtin(__builtin_amdgcn_fdot2)
  return __builtin_amdgcn_fdot2(__builtin_bit_cast(v2h, w), __builtin_bit_cast(v2h, h), c, false);
#else
  const __half2 wh = __builtin_bit_cast(__half2, w);
  const __half2 hh = __builtin_bit_cast(__half2, h);
  return c + __low2float(wh)*__low2float(hh) + __high2float(wh)*__high2float(hh);
#endif
}

__device__ __forceinline__ float artanh_c(float x){
  x = fminf(fmaxf(x, -CLIPF), CLIPF);
  return 0.5f * logf((1.0f + x) / (1.0f - x));
}
__device__ __forceinline__ float sigmoidf_(float x){ return 1.0f/(1.0f+expf(-x)); }
__device__ __forceinline__ float hsum4(float4 v){ return (v.x+v.y)+(v.z+v.w); }
__device__ __forceinline__ float sum8(const float* r){
  const float4* p = (const float4*)r;
  return hsum4(p[0]) + hsum4(p[1]);
}

__device__ __forceinline__ void postf(unsigned long long* p, float x, unsigned tag){
  unsigned long long v = ((unsigned long long)tag << 32) |
                         (unsigned long long)__float_as_uint(x);
  __hip_atomic_store(p, v, __ATOMIC_RELAXED, SCOPE_AGENT);
}
__device__ __forceinline__ float pollf(const unsigned long long* p, unsigned tag){
  unsigned long long v = __hip_atomic_load(p, __ATOMIC_RELAXED, SCOPE_AGENT);
  while ((unsigned)(v >> 32) != tag)
    v = __hip_atomic_load(p, __ATOMIC_RELAXED, SCOPE_AGENT);
  return __uint_as_float((unsigned)v);
}

// reduce NS values across the wave; lane0 stores red[s*8 + wave] (8 waves)
template<int NS>
__device__ __forceinline__ void wave_reduce_store(float (&v)[NS], float* red, int tid){
  #pragma unroll
  for (int off = 32; off > 0; off >>= 1)
    #pragma unroll
    for (int s = 0; s < NS; s++) v[s] += __shfl_xor(v[s], off);
  if ((tid & 63) == 0)
    #pragma unroll
    for (int s = 0; s < NS; s++) red[s*8 + (tid >> 6)] = v[s];
}

// full gate evaluation: mobius_matvec scale + 2x mobius_add + logmap0 + sigmoid
__device__ __forceinline__ float gate_val(float a, float y, float bv,
    float A2, float AY, float Y2, float AB, float YB, float B2,
    float xn, float art_h){
  const float mraw = sqrtf(A2);
  const float mnc = fmaxf(mraw, EPSF);
  const float alpha = (mraw <= EPSF) ? 0.f : (tanhf(mnc/xn*art_h)/mnc);
  const float X2 = alpha*alpha*A2, XY = alpha*AY, XB = alpha*AB;
  const float cA1 = 1.f + 2.f*XY + Y2, cB1 = 1.f - X2;
  const float den1 = fmaxf(1.f + 2.f*XY + X2*Y2, EPSF), id1 = 1.f/den1;
  const float T2 = fmaxf((cA1*cA1*X2 + 2.f*cA1*cB1*XY + cB1*cB1*Y2)*id1*id1, 0.f);
  const float TB = (cA1*XB + cB1*YB)*id1;
  const float cA2 = 1.f + 2.f*TB + B2, cB2 = 1.f - T2;
  const float den2 = fmaxf(1.f + 2.f*TB + T2*B2, EPSF), id2 = 1.f/den2;
  const float U2 = fmaxf((cA2*cA2*T2 + 2.f*cA2*cB2*TB + cB2*cB2*B2)*id2*id2, 0.f);
  const float un = fmaxf(sqrtf(U2), EPSF);
  const float lsc = artanh_c(un)/un;
  const float t1el = (cA1*(alpha*a) + cB1*y)*id1;
  const float uel  = (cA2*t1el + cB2*bv)*id2;
  return sigmoidf_(lsc*uel);
}

// ---- transpose weight_ih [1536][512] -> WihT [512][1536]
__global__ void k_prep_ih(const float* __restrict__ Wih, float* __restrict__ WihT){
  int i = blockIdx.x * blockDim.x + threadIdx.x;
  if (i >= H_ * G3_) return;
  int k = i / G3_, n = i % G3_;
  WihT[i] = Wih[n * H_ + k];
}

__device__ __forceinline__ uint4 pack8h(const float* s){
  __half2 p0 = __halves2half2(__float2half_rn(s[0]), __float2half_rn(s[1]));
  __half2 p1 = __halves2half2(__float2half_rn(s[2]), __float2half_rn(s[3]));
  __half2 p2 = __halves2half2(__float2half_rn(s[4]), __float2half_rn(s[5]));
  __half2 p3 = __halves2half2(__float2half_rn(s[6]), __float2half_rn(s[7]));
  uint4 r;
  r.x = __builtin_bit_cast(unsigned int, p0);
  r.y = __builtin_bit_cast(unsigned int, p1);
  r.z = __builtin_bit_cast(unsigned int, p2);
  r.w = __builtin_bit_cast(unsigned int, p3);
  return r;
}

// ---- weight_hh -> column-split layouts (f16, 8-k-wide uint4), same as R7
// WzrR[w][i<32][tid<512]: thread tid=(ks<<8)|c owns col j=128w+(c&127)
//   (c<128: z row=1024+j, else r row=j), k0 = ks*256 + i*8
// WhcR[w][q<4][i<16][c<128]: cand col j=128w+c (row 512+j), k0 = q*128 + i*8
__global__ void k_prep_hhR(const float* __restrict__ Whh, uint4* __restrict__ WzrR,
                           uint4* __restrict__ WhcR){
  int i = blockIdx.x * blockDim.x + threadIdx.x;   // 98304 total
  if (i < 65536){
    int w = i >> 14, rem = i & 16383;
    int ii = rem >> 9, tid = rem & 511;
    int c = tid & 255, ks = tid >> 8;
    int j = 128*w + (c & 127);
    int row = (c < 128) ? (1024 + j) : j;
    int k0 = ks*256 + ii*8;
    WzrR[i] = pack8h(Whh + row*H_ + k0);
  } else {
    int e = i - 65536;                              // 32768
    int w = e >> 13, rem = e & 8191;
    int q = rem >> 11, rem2 = rem & 2047;
    int ii = rem2 >> 7, c = rem2 & 127;
    int row = 512 + 128*w + c;
    int k0 = q*128 + ii*8;
    WhcR[e] = pack8h(Whh + row*H_ + k0);
  }
}

// ---- tiled f32 GEMM: C[16384][1536] = A[16384][512] * Bt[512][1536]
__global__ __launch_bounds__(256) void k_gemm(const float* __restrict__ A,
                                              const float* __restrict__ Bt,
                                              float* __restrict__ C){
  const int N = G3_, K = H_;
  const int mbase = blockIdx.x * 64, nbase = blockIdx.y * 64;
  __shared__ float As[32][65];
  __shared__ float Bs[32][65];
  const int tid = threadIdx.x;
  const int tm = tid >> 4, tn = tid & 15;
  float acc[4][4] = {};
  for (int k0 = 0; k0 < K; k0 += 32){
    #pragma unroll
    for (int i = 0; i < 8; i++){
      int e = tid + 256*i;
      int m = e >> 5, k = e & 31;
      As[k][m] = A[(size_t)(mbase + m) * K + k0 + k];
      int kk = e >> 6, n = e & 63;
      Bs[kk][n] = Bt[(size_t)(k0 + kk) * N + nbase + n];
    }
    __syncthreads();
    #pragma unroll
    for (int kk = 0; kk < 32; kk++){
      float av[4], bv[4];
      #pragma unroll
      for (int i = 0; i < 4; i++) av[i] = As[kk][tm*4+i];
      #pragma unroll
      for (int j = 0; j < 4; j++) bv[j] = Bs[kk][tn*4+j];
      #pragma unroll
      for (int i = 0; i < 4; i++)
        #pragma unroll
        for (int j = 0; j < 4; j++)
          acc[i][j] = fmaf(av[i], bv[j], acc[i][j]);
    }
    __syncthreads();
  }
  #pragma unroll
  for (int i = 0; i < 4; i++)
    #pragma unroll
    for (int j = 0; j < 4; j++)
      C[(size_t)(mbase + tm*4 + i) * N + nbase + tn*4 + j] = acc[i][j];
}

// ---- mobius_matvec tail on Ux rows
__global__ void k_nonlin(const float* __restrict__ X, float* __restrict__ D){
  const int row = blockIdx.x;
  const int lane = threadIdx.x;
  const float* x = X + (size_t)row * H_;
  float s = 0.0f;
  for (int k = lane; k < H_; k += 64){ float v = x[k]; s = fmaf(v, v, s); }
  #pragma unroll
  for (int off = 32; off > 0; off >>= 1) s += __shfl_xor(s, off);
  const float xn = fmaxf(sqrtf(s), EPSF);
  const float art = artanh_c(xn);
  float* drow = D + (size_t)row * G3_;
  for (int g = 0; g < 3; g++){
    float* mx = drow + g * H_;
    float s2 = 0.0f;
    for (int k = lane; k < H_; k += 64){ float v = mx[k]; s2 = fmaf(v, v, s2); }
    #pragma unroll
    for (int off = 32; off > 0; off >>= 1) s2 += __shfl_xor(s2, off);
    const float raw = sqrtf(s2);
    const float mn = fmaxf(raw, EPSF);
    const float scale = (raw <= EPSF) ? 0.0f : (tanhf(mn / xn * art) / mn);
    for (int k = lane; k < H_; k += 64) mx[k] *= scale;
  }
}

// ---- scan: 4 WGs/row (256 WGs x 512 thr), 2 exchange rounds + 7 bars per step
__global__ __launch_bounds__(512, 1) void k_scan(
    const float* __restrict__ D,        // Ux' [T*B][1536]: r|c|z col blocks
    const uint4* __restrict__ WzrR,     // [4][32][512]
    const uint4* __restrict__ WhcR,     // [4][4][16][128]
    const float* __restrict__ bias,     // [3][512] = b_r, b_c, b_z
    const float* __restrict__ h0,
    float* __restrict__ outbuf,         // [T][64][512]
    float* __restrict__ hlast,
    unsigned long long* __restrict__ AZ,    // [64][512]
    unsigned long long* __restrict__ AR,    // [64][512]
    unsigned long long* __restrict__ CEL,   // [64][512]
    unsigned tagbase)
{
  const int blk = blockIdx.x;
  const int b = blk & 63, w = blk >> 6;
  const int tid = threadIdx.x;
  __shared__ __align__(16) __half hh[H_];
  __shared__ __align__(16) __half wvh[H_];
  __shared__ __align__(16) float ph[512];
  __shared__ __align__(16) float redE[72];   // 9 poll-independent stats
  __shared__ __align__(16) float redA[48];   // 6 gate-dot stats
  __shared__ __align__(16) float redW[8];    // W2
  __shared__ __align__(16) float redC[32];   // 4 cand-dot stats
  __shared__ __align__(16) float redD[24];   // 3 final stats (also bias preamble)

  unsigned long long* azRow = AZ  + (size_t)b*512;
  unsigned long long* arRow = AR  + (size_t)b*512;
  unsigned long long* ceRow = CEL + (size_t)b*512;

  // ---- weight slices (compiler streams from L2; proven off critical path)
  const int ks = tid >> 8;                      // phase A k-half
  const int c2 = tid & 127, q = tid >> 7;       // phase B: col + k-quarter
  const uint4* wAb = WzrR + (size_t)w*32*512 + tid;
  const uint4* wBb = WhcR + ((size_t)(w*4 + q)*16)*128 + c2;
  uint4 wA[32];
  #pragma unroll
  for (int i = 0; i < 32; i++) wA[i] = wAb[i*512];
  uint4 wB[16];
  #pragma unroll
  for (int i = 0; i < 16; i++) wB[i] = wBb[i*128];

  // own h element in a register; f16 copy of full h in LDS
  float h_own = h0[b*H_ + tid];
  hh[tid] = __float2half_rn(h_own);

  const float bz = bias[1024 + tid], br = bias[tid], bc = bias[512 + tid];
  {
    float vb[3] = { bz*bz, br*br, bc*bc };
    wave_reduce_store<3>(vb, redD, tid);
  }
  __syncthreads();
  const float B2z = sum8(redD), B2r = sum8(redD+8), BC2 = sum8(redD+16);
  __syncthreads();

  const uint4* hh4 = (const uint4*)hh;
  const uint4* wv4 = (const uint4*)wvh;
  const float* Dbase = D + (size_t)b * G3_;
  const int jA = 128*w + (tid & 127);           // posting col (tid<256 / tid<128)
  const bool own = ((tid >> 7) == w);           // col tid owned by this WG

  for (int t = 0; t < T_; t++){
    const unsigned tag = tagbase + (unsigned)t + 1u;
    const float* U = Dbase + (size_t)t * (B_ * G3_);
    const float yr = U[tid], yc = U[512 + tid], yz = U[1024 + tid];

    // ---- phase A: column-split z/r dots (col tid&255, k-half ks)
    float ap = 0.f;
    #pragma unroll
    for (int i = 0; i < 32; i++){
      const uint4 wr = wA[i];
      const uint4 hp = hh4[ks*32 + i];
      ap = fdot2_(wr.x, hp.x, ap);
      ap = fdot2_(wr.y, hp.y, ap);
      ap = fdot2_(wr.z, hp.z, ap);
      ap = fdot2_(wr.w, hp.w, ap);
    }
    ph[tid] = ap;
    // poll-independent stats (hide under exchange)
    {
      float v[9] = { h_own*h_own, yz*yz, yz*bz, yr*yr, yr*br,
                     yc*yc, yc*bc, h_own*yc, h_own*bc };
      wave_reduce_store<9>(v, redE, tid);
    }
    __syncthreads();                                   // bar A
    if (tid < 256){
      const float a = ph[tid] + ph[tid + 256];
      postf(((tid < 128) ? azRow : arRow) + jA, a, tag);
    }
    // ---- round 1 gather: full a_z, a_r vectors (own cols via LDS)
    float az, ar;
    if (own){
      const int x = tid & 127;
      az = ph[x]       + ph[x + 256];
      ar = ph[x + 128] + ph[x + 384];
    } else {
      const unsigned long long* pz = azRow + tid;
      const unsigned long long* pr = arRow + tid;
      unsigned long long uz = __hip_atomic_load(pz, __ATOMIC_RELAXED, SCOPE_AGENT);
      unsigned long long ur = __hip_atomic_load(pr, __ATOMIC_RELAXED, SCOPE_AGENT);
      while ((unsigned)(uz >> 32) != tag)
        uz = __hip_atomic_load(pz, __ATOMIC_RELAXED, SCOPE_AGENT);
      while ((unsigned)(ur >> 32) != tag)
        ur = __hip_atomic_load(pr, __ATOMIC_RELAXED, SCOPE_AGENT);
      az = __uint_as_float((unsigned)uz);
      ar = __uint_as_float((unsigned)ur);
    }
    {
      float v[6] = { az*az, az*yz, az*bz, ar*ar, ar*yr, ar*br };
      wave_reduce_store<6>(v, redA, tid);
    }
    __syncthreads();                                   // bar B
    const float H2  = sum8(redE);
    const float Y2z = sum8(redE+8),  YBz = sum8(redE+16);
    const float Y2r = sum8(redE+24), YBr = sum8(redE+32);
    const float Y2c = sum8(redE+40), YBc = sum8(redE+48);
    const float HYd = sum8(redE+56), HBd = sum8(redE+64);
    const float A2z = sum8(redA), AYz = sum8(redA+8), ABz = sum8(redA+16);
    const float A2r = sum8(redA+24), AYr = sum8(redA+32), ABr = sum8(redA+40);

    const float xn = fmaxf(sqrtf(H2), EPSF);
    const float art_h = artanh_c(xn);
    const float zj = gate_val(az, yz, bz, A2z, AYz, Y2z, ABz, YBz, B2z, xn, art_h);
    const float rj = gate_val(ar, yr, br, A2r, AYr, Y2r, ABr, YBr, B2r, xn, art_h);
    const float wvv = rj * h_own;
    wvh[tid] = __float2half_rn(wvv);
    {
      float v1[1] = { wvv*wvv };
      wave_reduce_store<1>(v1, redW, tid);
    }
    __syncthreads();                                   // bar C
    const float W2 = sum8(redW);
    const float wraw = sqrtf(W2);
    const float wn = fmaxf(wraw, EPSF);
    const float mu = (wraw <= EPSF) ? 0.f : (tanhf(wn/xn*art_h)/wn);
    const float rhn = fmaxf(mu*wraw, EPSF);

    // ---- phase B: column-split cand dot (col c2, k-quarter q)
    float cp = 0.f;
    #pragma unroll
    for (int i = 0; i < 16; i++){
      const uint4 wr = wB[i];
      const uint4 rp = wv4[q*16 + i];
      cp = fdot2_(wr.x, rp.x, cp);
      cp = fdot2_(wr.y, rp.y, cp);
      cp = fdot2_(wr.z, rp.z, cp);
      cp = fdot2_(wr.w, rp.w, cp);
    }
    ph[tid] = cp;
    __syncthreads();                                   // bar D
    if (tid < 128){
      const float celo = mu * (ph[tid] + ph[tid+128] + ph[tid+256] + ph[tid+384]);
      postf(ceRow + jA, celo, tag);
    }
    // ---- round 2 gather: full cel vector
    float cel;
    if (own){
      const int x = tid & 127;
      cel = mu * (ph[x] + ph[x+128] + ph[x+256] + ph[x+384]);
    } else {
      cel = pollf(ceRow + tid, tag);
    }
    {
      float v[4] = { cel*cel, cel*yc, cel*bc, h_own*cel };
      wave_reduce_store<4>(v, redC, tid);
    }
    __syncthreads();                                   // bar E
    const float C2 = sum8(redC), CY = sum8(redC+8),
                CB = sum8(redC+16), HC = sum8(redC+24);
    const float craw = sqrtf(C2);
    const float cmn2 = fmaxf(craw, EPSF);
    const float alc = (craw <= EPSF) ? 0.f : (tanhf(cmn2/rhn*artanh_c(rhn))/cmn2);
    const float X2c = alc*alc*C2, XYc = alc*CY, XBc = alc*CB, HXc = alc*HC;
    const float cA1c = 1.f + 2.f*XYc + Y2c, cB1c = 1.f - X2c;
    const float den1c = fmaxf(1.f + 2.f*XYc + X2c*Y2c, EPSF), id1c = 1.f/den1c;
    const float T2c = fmaxf((cA1c*cA1c*X2c + 2.f*cA1c*cB1c*XYc + cB1c*cB1c*Y2c)*id1c*id1c, 0.f);
    const float TBc = (cA1c*XBc + cB1c*YBc)*id1c;
    const float HT1 = (cA1c*HXc + cB1c*HYd)*id1c;
    const float cA2c = 1.f + 2.f*TBc + BC2, cB2c = 1.f - T2c;
    const float den2c = fmaxf(1.f + 2.f*TBc + T2c*BC2, EPSF), id2c = 1.f/den2c;
    const float HTL2 = fmaxf((cA2c*cA2c*T2c + 2.f*cA2c*cB2c*TBc + cB2c*cB2c*BC2)*id2c*id2c, 0.f);
    const float HHTL = (cA2c*HT1 + cB2c*HBd)*id2c;
    const float cAd = 1.f - 2.f*HHTL + HTL2, cBd = 1.f - H2;
    const float dend = fmaxf(1.f - 2.f*HHTL + H2*HTL2, EPSF), idd = 1.f/dend;
    const float t1cel = (cA1c*(alc*cel) + cB1c*yc)*id1c;
    const float htlel = (cA2c*t1cel + cB2c*bc)*id2c;
    const float del = (cAd*(-h_own) + cBd*htlel)*idd;
    const float w2el = zj*del;
    {
      float v[3] = { del*del, w2el*w2el, h_own*w2el };
      wave_reduce_store<3>(v, redD, tid);
    }
    __syncthreads();                                   // bar F
    const float D2v = sum8(redD), W22 = sum8(redD+8), HW = sum8(redD+16);
    const float dnv = fmaxf(sqrtf(D2v), EPSF);
    const float w2raw = sqrtf(W22);
    const float w2n = fmaxf(w2raw, EPSF);
    const float nu = (w2raw <= EPSF) ? 0.f : (tanhf(w2n/dnv*artanh_c(dnv))/w2n);
    const float Y2f = nu*nu*W22, XYf = nu*HW;
    const float cAf = 1.f + 2.f*XYf + Y2f, cBf = 1.f - H2;
    const float denf = fmaxf(1.f + 2.f*XYf + H2*Y2f, EPSF), idf = 1.f/denf;
    const float hnew = (cAf*h_own + cBf*(nu*w2el))*idf;
    h_own = hnew;
    hh[tid] = __float2half_rn(hnew);
    if (w == 0){
      outbuf[(size_t)(t*B_ + b)*H_ + tid] = hnew;
      if (t == T_-1) hlast[b*H_ + tid] = hnew;
    }
    __syncthreads();                                   // bar G
  }
}

extern "C" void kernel_launch(void* const* d_in, const int* in_sizes, int n_in,
                              void* d_out, int out_size, void* d_ws, size_t ws_size,
                              hipStream_t stream){
  (void)in_sizes; (void)n_in; (void)out_size; (void)ws_size;
  const float* input = (const float*)d_in[0];
  const float* h0    = (const float*)d_in[1];
  const float* wih1  = (const float*)d_in[2];
  const float* wih2  = (const float*)d_in[3];
  const float* whh1  = (const float*)d_in[4];
  const float* whh2  = (const float*)d_in[5];
  const float* bias1 = (const float*)d_in[6];
  const float* bias2 = (const float*)d_in[7];
  float* out = (float*)d_out;

  // ws (floats): WihT 786432 | Dbuf 25165824 | WzrR 262144 | WhcR 131072 |
  //              AZ/AR/CEL 3 x 65536 (u64, shared by layers via tag ranges)
  float* A_    = (float*)d_ws;
  float* Dbuf  = A_ + 786432;
  uint4* WzrR  = (uint4*)(Dbuf + 25165824);
  uint4* WhcR  = WzrR + 65536;
  unsigned long long* AZ  = (unsigned long long*)(WhcR + 32768);
  unsigned long long* AR  = AZ + 32768;
  unsigned long long* CEL = AR + 32768;

  float* out1 = out;                          // staged; consumed before scan-2 overwrites
  float* ht   = out + (size_t)T_ * B_ * H_;

  // layer 1  (tags 1..256)
  k_prep_ih<<<3072, 256, 0, stream>>>(wih1, A_);
  k_gemm<<<dim3(256, 24), 256, 0, stream>>>(input, A_, Dbuf);
  k_nonlin<<<T_*B_, 64, 0, stream>>>(input, Dbuf);
  k_prep_hhR<<<384, 256, 0, stream>>>(whh1, WzrR, WhcR);
  k_scan<<<256, 512, 0, stream>>>(Dbuf, WzrR, WhcR, bias1, h0, out1, ht,
                                  AZ, AR, CEL, 0u);

  // layer 2  (tags 257..512; no aliasing with layer 1's 1..256)
  k_prep_ih<<<3072, 256, 0, stream>>>(wih2, A_);
  k_gemm<<<dim3(256, 24), 256, 0, stream>>>(out1, A_, Dbuf);
  k_nonlin<<<T_*B_, 64, 0, stream>>>(out1, Dbuf);
  k_prep_hhR<<<384, 256, 0, stream>>>(whh2, WzrR, WhcR);
  k_scan<<<256, 512, 0, stream>>>(Dbuf, WzrR, WhcR, bias2, h0 + B_*H_, out, ht + B_*H_,
                                  AZ, AR, CEL, 256u);
}

// Round 6
// 8706.644 us; speedup vs baseline: 1.2505x; 1.2505x over previous
//
#include <hip/hip_runtime.h>
#include <hip/hip_fp16.h>
#include <math.h>
#include <stdint.h>

// MobiusGRU T=256 B=64 D=H=512, 2 layers.
// R13 = R7/R9 base (verified 3340us/scan) with the S4 exchange hop DELETED
// algebraically: del_j is affine in {h, cel, yc, bc} with scalar coefficients
// known after the S3 scalars, so the S4 statistics (del^2, |z.*del|^2,
// h.(z.*del)) are quadratic forms over the basis Gram matrix. The S3 round is
// widened 8 -> 22 scalars (adds the z-weighted Gram entries; two waves gather
// in parallel, same hop latency) and the S4 post/poll + 2 barriers vanish.
// 4 LLC hops/step (was 5), 8 barriers (was 10). Elementwise del/w2el/hnew are
// still computed directly; only the 3 norms use the expansion. Comm fabric
// unchanged: fence-free tagged {tag,value} u64 relaxed agent atomics,
// monotone tags, same interlock argument.

#define T_  256
#define B_  64
#define H_  512
#define G3_ 1536
#define EPSF 1e-15f
#define CLIPF (1.0f - 1e-5f)
#define SCOPE_AGENT __HIP_MEMORY_SCOPE_AGENT

typedef _Float16 v2h __attribute__((ext_vector_type(2)));

__device__ __forceinline__ float fdot2_(unsigned int w, unsigned int h, float c){
#if __has_builtin(__builtin_amdgcn_fdot2)
  return __builtin_amdgcn_fdot2(__builtin_bit_cast(v2h, w), __builtin_bit_cast(v2h, h), c, false);
#else
  const __half2 wh = __builtin_bit_cast(__half2, w);
  const __half2 hh = __builtin_bit_cast(__half2, h);
  return c + __low2float(wh)*__low2float(hh) + __high2float(wh)*__high2float(hh);
#endif
}

__device__ __forceinline__ float artanh_c(float x){
  x = fminf(fmaxf(x, -CLIPF), CLIPF);
  return 0.5f * logf((1.0f + x) / (1.0f - x));
}
__device__ __forceinline__ float sigmoidf_(float x){ return 1.0f/(1.0f+expf(-x)); }
__device__ __forceinline__ float hsum4(float4 v){ return (v.x+v.y)+(v.z+v.w); }

// fence-free tagged exchange (relaxed agent atomics: no cache inv/wb)
__device__ __forceinline__ void postf(unsigned long long* p, float x, unsigned tag){
  unsigned long long v = ((unsigned long long)tag << 32) |
                         (unsigned long long)__float_as_uint(x);
  __hip_atomic_store(p, v, __ATOMIC_RELAXED, SCOPE_AGENT);
}
__device__ __forceinline__ float pollf(const unsigned long long* p, unsigned tag){
  unsigned long long v = __hip_atomic_load(p, __ATOMIC_RELAXED, SCOPE_AGENT);
  while ((unsigned)(v >> 32) != tag)
    v = __hip_atomic_load(p, __ATOMIC_RELAXED, SCOPE_AGENT);
  return __uint_as_float((unsigned)v);
}

// reduce NS values across the wave; lane0 stores red[s*8 + wave] (8 waves)
template<int NS>
__device__ __forceinline__ void wave_reduce_store(float (&v)[NS], float* red, int tid){
  #pragma unroll
  for (int off = 32; off > 0; off >>= 1)
    #pragma unroll
    for (int s = 0; s < NS; s++) v[s] += __shfl_xor(v[s], off);
  if ((tid & 63) == 0)
    #pragma unroll
    for (int s = 0; s < NS; s++) red[s*8 + (tid >> 6)] = v[s];
}

// ---- transpose weight_ih [1536][512] -> WihT [512][1536]
__global__ void k_prep_ih(const float* __restrict__ Wih, float* __restrict__ WihT){
  int i = blockIdx.x * blockDim.x + threadIdx.x;
  if (i >= H_ * G3_) return;
  int k = i / G3_, n = i % G3_;
  WihT[i] = Wih[n * H_ + k];
}

__device__ __forceinline__ uint4 pack8h(const float* s){
  __half2 p0 = __halves2half2(__float2half_rn(s[0]), __float2half_rn(s[1]));
  __half2 p1 = __halves2half2(__float2half_rn(s[2]), __float2half_rn(s[3]));
  __half2 p2 = __halves2half2(__float2half_rn(s[4]), __float2half_rn(s[5]));
  __half2 p3 = __halves2half2(__float2half_rn(s[6]), __float2half_rn(s[7]));
  uint4 r;
  r.x = __builtin_bit_cast(unsigned int, p0);
  r.y = __builtin_bit_cast(unsigned int, p1);
  r.z = __builtin_bit_cast(unsigned int, p2);
  r.w = __builtin_bit_cast(unsigned int, p3);
  return r;
}

// ---- weight_hh -> col-split layouts (f16, 8-k-wide uint4), as R7
__global__ void k_prep_hhR(const float* __restrict__ Whh, uint4* __restrict__ WzrR,
                           uint4* __restrict__ WhcR){
  int i = blockIdx.x * blockDim.x + threadIdx.x;   // 98304 total
  if (i < 65536){
    int w = i >> 14, rem = i & 16383;
    int ii = rem >> 9, tid = rem & 511;
    int c = tid & 255, ks = tid >> 8;
    int j = 128*w + (c & 127);
    int row = (c < 128) ? (1024 + j) : j;
    int k0 = ks*256 + ii*8;
    WzrR[i] = pack8h(Whh + row*H_ + k0);
  } else {
    int e = i - 65536;                              // 32768
    int w = e >> 13, rem = e & 8191;
    int q = rem >> 11, rem2 = rem & 2047;
    int ii = rem2 >> 7, c = rem2 & 127;
    int row = 512 + 128*w + c;
    int k0 = q*128 + ii*8;
    WhcR[e] = pack8h(Whh + row*H_ + k0);
  }
}

// ---- tiled f32 GEMM: C[16384][1536] = A[16384][512] * Bt[512][1536]
__global__ __launch_bounds__(256) void k_gemm(const float* __restrict__ A,
                                              const float* __restrict__ Bt,
                                              float* __restrict__ C){
  const int N = G3_, K = H_;
  const int mbase = blockIdx.x * 64, nbase = blockIdx.y * 64;
  __shared__ float As[32][65];
  __shared__ float Bs[32][65];
  const int tid = threadIdx.x;
  const int tm = tid >> 4, tn = tid & 15;
  float acc[4][4] = {};
  for (int k0 = 0; k0 < K; k0 += 32){
    #pragma unroll
    for (int i = 0; i < 8; i++){
      int e = tid + 256*i;
      int m = e >> 5, k = e & 31;
      As[k][m] = A[(size_t)(mbase + m) * K + k0 + k];
      int kk = e >> 6, n = e & 63;
      Bs[kk][n] = Bt[(size_t)(k0 + kk) * N + nbase + n];
    }
    __syncthreads();
    #pragma unroll
    for (int kk = 0; kk < 32; kk++){
      float av[4], bv[4];
      #pragma unroll
      for (int i = 0; i < 4; i++) av[i] = As[kk][tm*4+i];
      #pragma unroll
      for (int j = 0; j < 4; j++) bv[j] = Bs[kk][tn*4+j];
      #pragma unroll
      for (int i = 0; i < 4; i++)
        #pragma unroll
        for (int j = 0; j < 4; j++)
          acc[i][j] = fmaf(av[i], bv[j], acc[i][j]);
    }
    __syncthreads();
  }
  #pragma unroll
  for (int i = 0; i < 4; i++)
    #pragma unroll
    for (int j = 0; j < 4; j++)
      C[(size_t)(mbase + tm*4 + i) * N + nbase + tn*4 + j] = acc[i][j];
}

// ---- mobius_matvec tail on Ux rows
__global__ void k_nonlin(const float* __restrict__ X, float* __restrict__ D){
  const int row = blockIdx.x;
  const int lane = threadIdx.x;
  const float* x = X + (size_t)row * H_;
  float s = 0.0f;
  for (int k = lane; k < H_; k += 64){ float v = x[k]; s = fmaf(v, v, s); }
  #pragma unroll
  for (int off = 32; off > 0; off >>= 1) s += __shfl_xor(s, off);
  const float xn = fmaxf(sqrtf(s), EPSF);
  const float art = artanh_c(xn);
  float* drow = D + (size_t)row * G3_;
  for (int g = 0; g < 3; g++){
    float* mx = drow + g * H_;
    float s2 = 0.0f;
    for (int k = lane; k < H_; k += 64){ float v = mx[k]; s2 = fmaf(v, v, s2); }
    #pragma unroll
    for (int off = 32; off > 0; off >>= 1) s2 += __shfl_xor(s2, off);
    const float raw = sqrtf(s2);
    const float mn = fmaxf(raw, EPSF);
    const float scale = (raw <= EPSF) ? 0.0f : (tanhf(mn / xn * art) / mn);
    for (int k = lane; k < H_; k += 64) mx[k] *= scale;
  }
}

// ---- scan: 4 WGs/row (256 WGs x 512 thr), 4 hops + 8 barriers per step
__global__ __launch_bounds__(512, 1) void k_scan(
    const float* __restrict__ D,        // Ux' [T*B][1536]: r|c|z col blocks
    const uint4* __restrict__ WzrR,     // [4][32][512]
    const uint4* __restrict__ WhcR,     // [4][4][16][128]
    const float* __restrict__ bias,     // [3][512] = b_r, b_c, b_z
    const float* __restrict__ h0,
    float* __restrict__ outbuf,         // [T][64][512]
    float* __restrict__ hlast,
    unsigned long long* __restrict__ hS,    // [64][512]
    unsigned long long* __restrict__ wvS,   // [64][512]
    unsigned long long* __restrict__ S1s,   // [64][4][16]
    unsigned long long* __restrict__ S3s)   // [64][4][32]  (widened: 22 used)
{
  const int blk = blockIdx.x;
  const int b = blk & 63, w = blk >> 6;
  const int tid = threadIdx.x;
  const int lane = tid & 63, wave = tid >> 6;
  __shared__ __align__(16) __half hh[H_];
  __shared__ __align__(16) float hf[H_];
  __shared__ __align__(16) __half wvh[H_];
  __shared__ __align__(16) float ph[512];
  __shared__ __align__(16) float red[176];
  __shared__ __align__(16) float redW[8];
  __shared__ __align__(16) float xr[32];

  unsigned long long* hRow  = hS  + b*512;
  unsigned long long* wvRow = wvS + b*512;
  unsigned long long* s1Row = S1s + b*64;
  unsigned long long* s3Row = S3s + b*128;

  // ---- preload weight slices (compiler streams from L2; off critical path)
  const int ks = tid >> 8;                      // phase A k-half
  const int c2 = tid & 127, q = tid >> 7;       // phase B: col + k-quarter
  const uint4* wAb = WzrR + (size_t)w*32*512 + tid;
  const uint4* wBb = WhcR + ((size_t)(w*4 + q)*16)*128 + c2;
  uint4 wA[32];
  #pragma unroll
  for (int i = 0; i < 32; i++) wA[i] = wAb[i*512];
  uint4 wB[16];
  #pragma unroll
  for (int i = 0; i < 16; i++) wB[i] = wBb[i*128];

  // initial h
  {
    const float hv0 = h0[b*H_ + tid];
    hf[tid] = hv0;
    hh[tid] = __float2half_rn(hv0);
  }
  // bias values + (local) bias norms
  const int jg = 128*w + (tid & 127);           // gate/cand col for tid<256 / tid<128
  const bool isZ = (tid < 128);
  const bool isGate = (tid < 256);
  const float bval = isGate ? (isZ ? bias[1024 + jg] : bias[jg]) : 0.f;
  const float bcj  = isZ ? bias[512 + jg] : 0.f;
  float B2own, BC2;
  {
    const float vz = bias[1024 + tid], vr = bias[tid], vc = bias[512 + tid];
    float vb[3] = { vz*vz, vr*vr, vc*vc };
    wave_reduce_store<3>(vb, red, tid);
    __syncthreads();
    const float4* p = (const float4*)red;
    const float B2z = hsum4(p[0]) + hsum4(p[1]);
    const float B2r = hsum4(p[2]) + hsum4(p[3]);
    BC2 = hsum4(p[4]) + hsum4(p[5]);
    B2own = isZ ? B2z : B2r;
    __syncthreads();
  }

  const uint4* hh4 = (const uint4*)hh;
  const uint4* wv4 = (const uint4*)wvh;
  const float* Dbase = D + (size_t)b * G3_;

  float zreg = 0.f;
  for (int t = 0; t < T_; t++){
    const unsigned tag = (unsigned)(t + 1);
    const float* U = Dbase + (size_t)t * (B_ * G3_);
    // Ux loads issue early
    const float yg = isGate ? U[(isZ ? 1024 : 0) + jg] : 0.f;
    const float yc = isZ ? U[512 + jg] : 0.f;

    // ---- h gather (posted with tag t by step t-1)
    if (t > 0){
      const float hv = pollf(hRow + tid, (unsigned)t);
      hf[tid] = hv;
      hh[tid] = __float2half_rn(hv);
    }
    __syncthreads();                                   // bar1
    const float hv = hf[tid];

    // ---- phase A: register x LDS-broadcast dot (col tid&255, k-half ks)
    float ap = 0.f;
    #pragma unroll
    for (int i = 0; i < 32; i++){
      const uint4 wr = wA[i];
      const uint4 hp = hh4[ks*32 + i];
      ap = fdot2_(wr.x, hp.x, ap);
      ap = fdot2_(wr.y, hp.y, ap);
      ap = fdot2_(wr.z, hp.z, ap);
      ap = fdot2_(wr.w, hp.w, ap);
    }
    ph[tid] = ap;
    __syncthreads();                                   // bar2
    const float a = isGate ? (ph[tid] + ph[tid + 256]) : 0.f;

    // ---- S1: local 11-slot reduce (slot0=h2 local-only; 10 gate dots exchanged)
    {
      float v[11];
      v[0] = hv*hv;
      #pragma unroll
      for (int s = 1; s < 11; s++) v[s] = 0.f;
      if (isGate){
        const int o = isZ ? 1 : 6;
        v[o] = a*a; v[o+1] = a*yg; v[o+2] = yg*yg; v[o+3] = a*bval; v[o+4] = yg*bval;
      }
      wave_reduce_store<11>(v, red, tid);
    }
    __syncthreads();                                   // bar3
    float H2;
    { const float4* p = (const float4*)red; H2 = hsum4(p[0]) + hsum4(p[1]); }
    if (wave == 0 && lane < 10){
      float s = 0.f;
      const float* r = red + (1 + lane)*8;
      #pragma unroll
      for (int i = 0; i < 8; i++) s += r[i];
      postf(s1Row + w*16 + lane, s, tag);
    }
    if (wave == 0){
      const int wgi = lane >> 4, s = lane & 15;
      float v = (s < 10) ? pollf(s1Row + wgi*16 + s, tag) : 0.f;
      v += __shfl_xor(v, 16);
      v += __shfl_xor(v, 32);
      if (lane < 16) xr[lane] = v;
    }
    __syncthreads();                                   // bar4

    // ---- gate math (threads 0..255)
    const float xn = fmaxf(sqrtf(H2), EPSF);
    const float art_h = artanh_c(xn);
    if (isGate){
      const int o = isZ ? 0 : 5;
      const float A2 = xr[o], AY = xr[o+1], Yy2 = xr[o+2], AB = xr[o+3], YB = xr[o+4];
      const float mraw = sqrtf(A2);
      const float mnc = fmaxf(mraw, EPSF);
      const float alpha = (mraw <= EPSF) ? 0.f : (tanhf(mnc/xn*art_h)/mnc);
      const float X2 = alpha*alpha*A2, XY = alpha*AY, XB = alpha*AB;
      const float cA1 = 1.f + 2.f*XY + Yy2, cB1 = 1.f - X2;
      const float den1 = fmaxf(1.f + 2.f*XY + X2*Yy2, EPSF), id1 = 1.f/den1;
      const float T2 = fmaxf((cA1*cA1*X2 + 2.f*cA1*cB1*XY + cB1*cB1*Yy2)*id1*id1, 0.f);
      const float TB = (cA1*XB + cB1*YB)*id1;
      const float cA2 = 1.f + 2.f*TB + B2own, cB2 = 1.f - T2;
      const float den2 = fmaxf(1.f + 2.f*TB + T2*B2own, EPSF), id2 = 1.f/den2;
      const float U2 = fmaxf((cA2*cA2*T2 + 2.f*cA2*cB2*TB + cB2*cB2*B2own)*id2*id2, 0.f);
      const float un = fmaxf(sqrtf(U2), EPSF);
      const float lsc = artanh_c(un)/un;
      const float t1el = (cA1*(alpha*a) + cB1*yg)*id1;
      const float uel  = (cA2*t1el + cB2*bval)*id2;
      const float g = sigmoidf_(lsc*uel);
      if (isZ) zreg = g;
      else postf(wvRow + jg, g * hf[jg], tag);
    }
    // ---- wv gather + local W2 reduce
    const float wvv = pollf(wvRow + tid, tag);
    wvh[tid] = __float2half_rn(wvv);
    {
      float v1[1] = { wvv*wvv };
      wave_reduce_store<1>(v1, redW, tid);
    }
    __syncthreads();                                   // bar5
    float W2;
    { const float4* p = (const float4*)redW; W2 = hsum4(p[0]) + hsum4(p[1]); }
    const float wraw = sqrtf(W2);
    const float wn = fmaxf(wraw, EPSF);
    const float mu = (wraw <= EPSF) ? 0.f : (tanhf(wn/xn*art_h)/wn);
    const float rhn = fmaxf(mu*wraw, EPSF);

    // ---- phase B: register x LDS-broadcast dot (col c2, k-quarter q)
    float cp = 0.f;
    #pragma unroll
    for (int i = 0; i < 16; i++){
      const uint4 wr = wB[i];
      const uint4 rp = wv4[q*16 + i];
      cp = fdot2_(wr.x, rp.x, cp);
      cp = fdot2_(wr.y, rp.y, cp);
      cp = fdot2_(wr.z, rp.z, cp);
      cp = fdot2_(wr.w, rp.w, cp);
    }
    ph[tid] = cp;
    __syncthreads();                                   // bar6
    float cel = 0.f, hj = 0.f;
    if (isZ){
      cel = mu * (ph[tid] + ph[tid+128] + ph[tid+256] + ph[tid+384]);
      hj  = hf[jg];
    }
    // ---- S3 (merged with S4): 8 cand Gram entries + 14 z-weighted entries
    {
      const float z2 = zreg*zreg;
      float v[22] = {
        cel*cel, cel*yc, yc*yc, cel*bcj, yc*bcj, hj*cel, hj*yc, hj*bcj,
        z2*hj*hj, z2*hj*cel, z2*hj*yc, z2*hj*bcj,
        z2*cel*cel, z2*cel*yc, z2*cel*bcj,
        z2*yc*yc, z2*yc*bcj, z2*bcj*bcj,
        zreg*hj*hj, zreg*hj*cel, zreg*hj*yc, zreg*hj*bcj };
      wave_reduce_store<22>(v, red, tid);
    }
    __syncthreads();                                   // bar7
    if (wave == 0 && lane < 22){
      float s = 0.f;
      const float* r = red + lane*8;
      #pragma unroll
      for (int i = 0; i < 8; i++) s += r[i];
      postf(s3Row + w*32 + lane, s, tag);
    }
    if (wave == 0){
      const int wgi = lane >> 4, s = lane & 15;
      float v = (s < 16) ? pollf(s3Row + wgi*32 + s, tag) : 0.f;
      v += __shfl_xor(v, 16);
      v += __shfl_xor(v, 32);
      if (lane < 16) xr[lane] = v;
    }
    if (wave == 1){
      const int wgi = lane >> 4, s = 16 + (lane & 15);
      float v = (s < 22) ? pollf(s3Row + wgi*32 + s, tag) : 0.f;
      v += __shfl_xor(v, 16);
      v += __shfl_xor(v, 32);
      if (lane < 16) xr[16 + lane] = v;
    }
    __syncthreads();                                   // bar8
    const float C2 = xr[0], CY = xr[1], Y2c = xr[2], CB = xr[3],
                YBc = xr[4], HC = xr[5], HYd = xr[6], HBd = xr[7];
    const float Z2HH = xr[8],  Z2HC = xr[9],  Z2HY = xr[10], Z2HB = xr[11];
    const float Z2CC = xr[12], Z2CY = xr[13], Z2CB = xr[14];
    const float Z2YY = xr[15], Z2YB = xr[16], Z2BB = xr[17];
    const float ZHH  = xr[18], ZHC  = xr[19], ZHY  = xr[20], ZHB  = xr[21];

    const float craw = sqrtf(C2);
    const float cmn2 = fmaxf(craw, EPSF);
    const float alc = (craw <= EPSF) ? 0.f : (tanhf(cmn2/rhn*artanh_c(rhn))/cmn2);
    const float X2c = alc*alc*C2, XYc = alc*CY, XBc = alc*CB, HXc = alc*HC;
    const float cA1c = 1.f + 2.f*XYc + Y2c, cB1c = 1.f - X2c;
    const float den1c = fmaxf(1.f + 2.f*XYc + X2c*Y2c, EPSF), id1c = 1.f/den1c;
    const float T2c = fmaxf((cA1c*cA1c*X2c + 2.f*cA1c*cB1c*XYc + cB1c*cB1c*Y2c)*id1c*id1c, 0.f);
    const float TBc = (cA1c*XBc + cB1c*YBc)*id1c;
    const float HT1 = (cA1c*HXc + cB1c*HYd)*id1c;
    const float cA2c = 1.f + 2.f*TBc + BC2, cB2c = 1.f - T2c;
    const float den2c = fmaxf(1.f + 2.f*TBc + T2c*BC2, EPSF), id2c = 1.f/den2c;
    const float HTL2 = fmaxf((cA2c*cA2c*T2c + 2.f*cA2c*cB2c*TBc + cB2c*cB2c*BC2)*id2c*id2c, 0.f);
    const float HHTL = (cA2c*HT1 + cB2c*HBd)*id2c;
    const float cAd = 1.f - 2.f*HHTL + HTL2, cBd = 1.f - H2;
    const float dend = fmaxf(1.f - 2.f*HHTL + H2*HTL2, EPSF), idd = 1.f/dend;

    // del_j = Af*h_j + Bf*cel_j + Cf*yc_j + Ef*bc_j  (same algebra as direct form)
    const float Pc = id2c*cA2c*id1c*cA1c*alc;
    const float Qc = id2c*cA2c*id1c*cB1c;
    const float Rc = id2c*cB2c;
    const float Af = -idd*cAd;
    const float Bf = idd*cBd*Pc, Cf = idd*cBd*Qc, Ef = idd*cBd*Rc;
    // S4 stats via Gram expansion (exchange-free)
    const float D2v = fmaxf(
        Af*Af*H2 + Bf*Bf*C2 + Cf*Cf*Y2c + Ef*Ef*BC2
      + 2.f*(Af*Bf*HC + Af*Cf*HYd + Af*Ef*HBd + Bf*Cf*CY + Bf*Ef*CB + Cf*Ef*YBc), 0.f);
    const float W22 = fmaxf(
        Af*Af*Z2HH + Bf*Bf*Z2CC + Cf*Cf*Z2YY + Ef*Ef*Z2BB
      + 2.f*(Af*Bf*Z2HC + Af*Cf*Z2HY + Af*Ef*Z2HB + Bf*Cf*Z2CY + Bf*Ef*Z2CB + Cf*Ef*Z2YB), 0.f);
    const float HW = Af*ZHH + Bf*ZHC + Cf*ZHY + Ef*ZHB;

    const float dnv = fmaxf(sqrtf(D2v), EPSF);
    const float w2raw = sqrtf(W22);
    const float w2n = fmaxf(w2raw, EPSF);
    const float nu = (w2raw <= EPSF) ? 0.f : (tanhf(w2n/dnv*artanh_c(dnv))/w2n);
    const float Y2f = nu*nu*W22, XYf = nu*HW;
    const float cAf = 1.f + 2.f*XYf + Y2f, cBf = 1.f - H2;
    const float denf = fmaxf(1.f + 2.f*XYf + H2*Y2f, EPSF), idf = 1.f/denf;
    if (isZ){
      // elementwise del/w2el computed directly (full precision path)
      const float t1cel = (cA1c*(alc*cel) + cB1c*yc)*id1c;
      const float htlel = (cA2c*t1cel + cB2c*bcj)*id2c;
      const float del = (cAd*(-hj) + cBd*htlel)*idd;
      const float w2el = zreg*del;
      const float hnew = (cAf*hj + cBf*(nu*w2el))*idf;
      outbuf[(size_t)(t*B_ + b)*H_ + jg] = hnew;
      postf(hRow + jg, hnew, tag);         // tag t+1, polled by step t+1
      if (t == T_-1) hlast[b*H_ + jg] = hnew;
    }
  }
}

extern "C" void kernel_launch(void* const* d_in, const int* in_sizes, int n_in,
                              void* d_out, int out_size, void* d_ws, size_t ws_size,
                              hipStream_t stream){
  (void)in_sizes; (void)n_in; (void)out_size; (void)ws_size;
  const float* input = (const float*)d_in[0];
  const float* h0    = (const float*)d_in[1];
  const float* wih1  = (const float*)d_in[2];
  const float* wih2  = (const float*)d_in[3];
  const float* whh1  = (const float*)d_in[4];
  const float* whh2  = (const float*)d_in[5];
  const float* bias1 = (const float*)d_in[6];
  const float* bias2 = (const float*)d_in[7];
  float* out = (float*)d_out;

  // ws (floats): WihT 786432 | Dbuf 25165824 | WzrR 262144 | WhcR 131072
  //              per-layer comm x2 (u64): hS 32768 | wvS 32768 | S1 4096 | S3 8192
  float* A_    = (float*)d_ws;
  float* Dbuf  = A_ + 786432;
  uint4* WzrR  = (uint4*)(Dbuf + 25165824);
  uint4* WhcR  = WzrR + 65536;
  float* comm0 = (float*)(WhcR + 32768);
  unsigned long long* hS1  = (unsigned long long*)comm0;
  unsigned long long* wvS1 = hS1  + 32768;
  unsigned long long* S1a  = wvS1 + 32768;
  unsigned long long* S3a  = S1a  + 4096;
  unsigned long long* hS2  = S3a  + 8192;
  unsigned long long* wvS2 = hS2  + 32768;
  unsigned long long* S1b  = wvS2 + 32768;
  unsigned long long* S3b  = S1b  + 4096;

  float* out1 = out;                          // staged; consumed before scan-2 overwrites
  float* ht   = out + (size_t)T_ * B_ * H_;

  // layer 1
  k_prep_ih<<<3072, 256, 0, stream>>>(wih1, A_);
  k_gemm<<<dim3(256, 24), 256, 0, stream>>>(input, A_, Dbuf);
  k_nonlin<<<T_*B_, 64, 0, stream>>>(input, Dbuf);
  k_prep_hhR<<<384, 256, 0, stream>>>(whh1, WzrR, WhcR);
  k_scan<<<256, 512, 0, stream>>>(Dbuf, WzrR, WhcR, bias1, h0, out1, ht,
                                  hS1, wvS1, S1a, S3a);

  // layer 2
  k_prep_ih<<<3072, 256, 0, stream>>>(wih2, A_);
  k_gemm<<<dim3(256, 24), 256, 0, stream>>>(out1, A_, Dbuf);
  k_nonlin<<<T_*B_, 64, 0, stream>>>(out1, Dbuf);
  k_prep_hhR<<<384, 256, 0, stream>>>(whh2, WzrR, WhcR);
  k_scan<<<256, 512, 0, stream>>>(Dbuf, WzrR, WhcR, bias2, h0 + B_*H_, out, ht + B_*H_,
                                  hS2, wvS2, S1b, S3b);
}